// Round 15
// baseline (119.537 us; speedup 1.0000x reference)
//
#include <hip/hip_runtime.h>

#define DD 128
#define NTC 8              // 8 col-tiles of 128 -> Cpad = 1024
#define NCOPY 8            // B replicas
#define COPYBYTES (NTC * 16384)   // 128 KB per replica
#define NGRP 4             // DIAGNOSTIC: row-groups per block (grid 64)

typedef __attribute__((ext_vector_type(4))) float f32x4;
typedef long long i64;

typedef __attribute__((address_space(1))) const void gvoid_t;
typedef __attribute__((address_space(3))) void svoid_t;
#define GLOAD_LDS16(g, s) __builtin_amdgcn_global_load_lds((gvoid_t*)(g), (svoid_t*)(s), 16, 0, 0)

__device__ __forceinline__ unsigned pk8(float a, float b, float c, float d) {
    int v = __builtin_amdgcn_cvt_pk_fp8_f32(a, b, 0, false);
    v = __builtin_amdgcn_cvt_pk_fp8_f32(c, d, v, true);
    return (unsigned)v;
}

// ---------- prep: centers -> fp8 e4m3, swizzled, 8 replicas + csq_half x8 ----------
__global__ void prep_centers(const float* __restrict__ ctr,
                             unsigned char* __restrict__ wsB,
                             float* __restrict__ csqh, int C, int Cpad) {
    int gid = blockIdx.x * 256 + threadIdx.x;
    int col = gid >> 2, q = gid & 3;
    if (col >= Cpad) return;
    const float* src = ctr + (size_t)col * DD + q * 32;
    const int r = col & 127;
    const unsigned tbase = (unsigned)(col >> 7) * 16384u + (unsigned)r * 128u;
    const unsigned sw = ((unsigned)r & 15u) << 3;
    float cs = 0.f;
    uint2 uu[4];
    #pragma unroll
    for (int m = 0; m < 4; ++m) {
        float4 v0 = make_float4(0.f,0.f,0.f,0.f), v1 = v0;
        if (col < C) {
            v0 = *(const float4*)(src + m * 8);
            v1 = *(const float4*)(src + m * 8 + 4);
        }
        cs = fmaf(v0.x,v0.x,cs); cs = fmaf(v0.y,v0.y,cs);
        cs = fmaf(v0.z,v0.z,cs); cs = fmaf(v0.w,v0.w,cs);
        cs = fmaf(v1.x,v1.x,cs); cs = fmaf(v1.y,v1.y,cs);
        cs = fmaf(v1.z,v1.z,cs); cs = fmaf(v1.w,v1.w,cs);
        uu[m].x = pk8(v0.x, v0.y, v0.z, v0.w);
        uu[m].y = pk8(v1.x, v1.y, v1.z, v1.w);
    }
    #pragma unroll
    for (int cp = 0; cp < NCOPY; ++cp) {
        unsigned char* dst = wsB + (unsigned)cp * (unsigned)COPYBYTES + tbase;
        #pragma unroll
        for (int m = 0; m < 4; ++m)
            *(uint2*)(dst + ((((unsigned)(q * 4 + m)) * 8u) ^ sw)) = uu[m];
    }
    cs += __shfl_xor(cs, 1); cs += __shfl_xor(cs, 2);
    if (q == 0) {
        float v = (col < C) ? 0.5f * cs : 1e30f;
        #pragma unroll
        for (int cp = 0; cp < NCOPY; ++cp) csqh[cp * 1024 + col] = v;
    }
}

// ---------- DIAGNOSTIC main: 64 blocks x 512 thr; 4 sequential 128-row groups ----------
__global__ __launch_bounds__(512, 1) void center_diag(
    const float* __restrict__ emb, const int* __restrict__ tgt,
    const float* __restrict__ ctr, const unsigned char* __restrict__ wsB,
    const float* __restrict__ csqh, float* __restrict__ partials)
{
    __shared__ uint4 sB4[8192];   // 128 KB resident fp8 B
    __shared__ uint4 sA4[1024];   // 16 KB A
    __shared__ float sRT[128];
    __shared__ float sRed[8];
    unsigned char* sAb = (unsigned char*)sA4;
    const unsigned char* sBb = (const unsigned char*)sB4;

    const int t = threadIdx.x;
    const int bid = blockIdx.x;
    const int cp = bid & (NCOPY - 1);
    const unsigned char* wsBx = wsB + (size_t)cp * COPYBYTES;
    const float* csqx = csqh + cp * 1024;

    const int l  = t & 63;
    const int w  = t >> 6;
    const int wr = w >> 2;
    const int wc = w & 3;
    const int li = l & 15;
    const int lh = l >> 4;
    const unsigned sw = (unsigned)li << 3;
    const int r = t >> 2, q = t & 3;

    // ---- B one-time load + csq hoist (amortized over 4 groups) ----
    #pragma unroll
    for (int i = 0; i < 16; ++i) {
        unsigned off = (unsigned)(i * 512 + t) * 16u;
        GLOAD_LDS16(wsBx + off, (unsigned char*)sB4 + off);
    }
    float cqa[NTC], cqb[NTC];
    #pragma unroll
    for (int nt = 0; nt < NTC; ++nt) {
        cqa[nt] = csqx[nt*128 + wc*32 + li];
        cqb[nt] = csqx[nt*128 + wc*32 + 16 + li];
    }

    #pragma unroll 1
    for (int g = 0; g < NGRP; ++g) {
        const int row0 = (bid + 64 * g) * 128;

        // issue A loads
        const float* srcE = emb + (size_t)(row0 + r) * DD + q * 32;
        const int y = tgt[row0 + r];
        const float* srcC = ctr + (size_t)y * DD + q * 32;
        float4 ev[8], cv[8];
        #pragma unroll
        for (int m = 0; m < 8; ++m) ev[m] = *(const float4*)(srcE + m * 4);
        #pragma unroll
        for (int m = 0; m < 8; ++m) cv[m] = *(const float4*)(srcC + m * 4);

        __syncthreads();   // prev group's K-loop done reading sA (harmless at g=0)

        // A-pack: rt_half + fp8 + swizzled LDS write
        {
            const unsigned swA = ((unsigned)r & 15u) << 3;
            float se = 0.f, sd = 0.f;
            #pragma unroll
            for (int m = 0; m < 4; ++m) {
                float4 e0 = ev[2*m], e1 = ev[2*m+1], c0 = cv[2*m], c1 = cv[2*m+1];
                se = fmaf(e0.x,e0.x,se); se = fmaf(e0.y,e0.y,se);
                se = fmaf(e0.z,e0.z,se); se = fmaf(e0.w,e0.w,se);
                se = fmaf(e1.x,e1.x,se); se = fmaf(e1.y,e1.y,se);
                se = fmaf(e1.z,e1.z,se); se = fmaf(e1.w,e1.w,se);
                float d;
                d = e0.x-c0.x; sd = fmaf(d,d,sd);  d = e0.y-c0.y; sd = fmaf(d,d,sd);
                d = e0.z-c0.z; sd = fmaf(d,d,sd);  d = e0.w-c0.w; sd = fmaf(d,d,sd);
                d = e1.x-c1.x; sd = fmaf(d,d,sd);  d = e1.y-c1.y; sd = fmaf(d,d,sd);
                d = e1.z-c1.z; sd = fmaf(d,d,sd);  d = e1.w-c1.w; sd = fmaf(d,d,sd);
                uint2 u;
                u.x = pk8(e0.x, e0.y, e0.z, e0.w);
                u.y = pk8(e1.x, e1.y, e1.z, e1.w);
                *(uint2*)(sAb + (unsigned)r * 128u +
                          ((((unsigned)(q * 4 + m)) * 8u) ^ swA)) = u;
            }
            se += __shfl_xor(se, 1); se += __shfl_xor(se, 2);
            sd += __shfl_xor(sd, 1); sd += __shfl_xor(sd, 2);
            if (q == 0) sRT[r] = 0.5f * (1.0f + sd - se);
        }
        __syncthreads();   // A writes (+B at g=0) visible

        i64 aF[4][4];
        #pragma unroll
        for (int mf = 0; mf < 4; ++mf)
            #pragma unroll
            for (int ks = 0; ks < 4; ++ks)
                aF[mf][ks] = *(const i64*)(sAb + (unsigned)(wr*64 + 16*mf + li) * 128u +
                                           (((unsigned)(8*lh + 32*ks)) ^ sw));
        float rtv[16];
        #pragma unroll
        for (int mf = 0; mf < 4; ++mf)
            #pragma unroll
            for (int rr = 0; rr < 4; ++rr)
                rtv[mf*4+rr] = sRT[wr*64 + 16*mf + 4*lh + rr];

        float tsum = 0.f;

        #pragma unroll
        for (int nt = 0; nt < NTC; ++nt) {
            i64 bF0[4], bF1[4];
            #pragma unroll
            for (int ks = 0; ks < 4; ++ks) {
                unsigned kof = ((unsigned)(8*lh + 32*ks)) ^ sw;
                bF0[ks] = *(const i64*)(sBb + (unsigned)nt*16384u +
                                        (unsigned)(wc*32 + li) * 128u + kof);
                bF1[ks] = *(const i64*)(sBb + (unsigned)nt*16384u +
                                        (unsigned)(wc*32 + 16 + li) * 128u + kof);
            }

            f32x4 acc[4][2];
            #pragma unroll
            for (int mf = 0; mf < 4; ++mf)
                #pragma unroll
                for (int rr = 0; rr < 4; ++rr) {
                    acc[mf][0][rr] = rtv[mf*4+rr] - cqa[nt];
                    acc[mf][1][rr] = rtv[mf*4+rr] - cqb[nt];
                }

            #pragma unroll
            for (int ks = 0; ks < 4; ++ks)
                #pragma unroll
                for (int mf = 0; mf < 4; ++mf) {
                    acc[mf][0] = __builtin_amdgcn_mfma_f32_16x16x32_fp8_fp8(aF[mf][ks], bF0[ks], acc[mf][0], 0, 0, 0);
                    acc[mf][1] = __builtin_amdgcn_mfma_f32_16x16x32_fp8_fp8(aF[mf][ks], bF1[ks], acc[mf][1], 0, 0, 0);
                }

            float s0 = 0.f, s1 = 0.f;
            #pragma unroll
            for (int mf = 0; mf < 4; ++mf)
                #pragma unroll
                for (int rr = 0; rr < 4; ++rr) {
                    s0 = fmaf(2.0f, fmaxf(acc[mf][0][rr], 0.f), s0);
                    s1 = fmaf(2.0f, fmaxf(acc[mf][1][rr], 0.f), s1);
                }
            tsum += s0 + s1;
        }

        // per-group block reduction
        float s = tsum;
        #pragma unroll
        for (int off = 32; off; off >>= 1) s += __shfl_down(s, off);
        if (l == 0) sRed[w] = s;
        __syncthreads();
        if (t == 0) {
            float bs = 0.f;
            #pragma unroll
            for (int i = 0; i < 8; ++i) bs += sRed[i];
            partials[bid + 64 * g] = bs;
        }
    }
}

// ---------- final reduction ----------
__global__ void reduce_k(const float* __restrict__ partials, int n,
                         float* __restrict__ out, double diagSub, double invDenom) {
    __shared__ double sRed[4];
    int t = threadIdx.x;
    double s = 0.0;
    for (int i = t; i < n; i += 256) s += (double)partials[i];
    #pragma unroll
    for (int off = 32; off; off >>= 1) s += __shfl_down(s, off);
    if ((t & 63) == 0) sRed[t >> 6] = s;
    __syncthreads();
    if (t == 0) out[0] = (float)(((sRed[0]+sRed[1]+sRed[2]+sRed[3]) - diagSub) * invDenom);
}

extern "C" void kernel_launch(void* const* d_in, const int* in_sizes, int n_in,
                              void* d_out, int out_size, void* d_ws, size_t ws_size,
                              hipStream_t stream) {
    const float* emb = (const float*)d_in[0];
    const int*   tgt = (const int*)d_in[1];
    const float* ctr = (const float*)d_in[2];

    const int B = in_sizes[1];                 // 32768
    const int C = in_sizes[2] / DD;            // 1000
    const int Cpad = NTC * 128;                // 1024
    const int nblk = 64;                       // DIAGNOSTIC grid
    const int nparts = B / 128;                // 256 partials

    unsigned char* wsB = (unsigned char*)d_ws;
    float* csqh = (float*)(wsB + (size_t)NCOPY * COPYBYTES);
    float* partials = csqh + NCOPY * 1024;

    prep_centers<<<(Cpad * 4) / 256, 256, 0, stream>>>(ctr, wsB, csqh, C, Cpad);
    center_diag<<<nblk, 512, 0, stream>>>(emb, tgt, ctr, wsB, csqh, partials);
    reduce_k<<<1, 256, 0, stream>>>(partials, nparts, (float*)d_out,
                                    (double)B,
                                    1.0 / ((double)B * (double)(C - 1)));
}

// Round 16
// 45.880 us; speedup vs baseline: 2.6054x; 2.6054x over previous
//
#include <hip/hip_runtime.h>

#define DD 128
#define NTC 8              // 8 col-tiles of 128 -> Cpad = 1024
#define NCOPY 8            // B replicas (one per XCD under round-robin)
#define COPYBYTES (NTC * 16384)   // 128 KB per replica

typedef __attribute__((ext_vector_type(4))) float f32x4;
typedef long long i64;

typedef __attribute__((address_space(1))) const void gvoid_t;
typedef __attribute__((address_space(3))) void svoid_t;
#define GLOAD_LDS16(g, s) __builtin_amdgcn_global_load_lds((gvoid_t*)(g), (svoid_t*)(s), 16, 0, 0)

__device__ __forceinline__ unsigned pk8(float a, float b, float c, float d) {
    int v = __builtin_amdgcn_cvt_pk_fp8_f32(a, b, 0, false);
    v = __builtin_amdgcn_cvt_pk_fp8_f32(c, d, v, true);
    return (unsigned)v;
}

// ---------- prep: centers -> fp8 e4m3, swizzled, 8 replicas + csq_half x8 ----------
__global__ void prep_centers(const float* __restrict__ ctr,
                             unsigned char* __restrict__ wsB,
                             float* __restrict__ csqh, int C, int Cpad) {
    int gid = blockIdx.x * 256 + threadIdx.x;
    int col = gid >> 2, q = gid & 3;
    if (col >= Cpad) return;
    const float* src = ctr + (size_t)col * DD + q * 32;
    const int r = col & 127;
    const unsigned tbase = (unsigned)(col >> 7) * 16384u + (unsigned)r * 128u;
    const unsigned sw = ((unsigned)r & 15u) << 3;
    float cs = 0.f;
    uint2 uu[4];
    #pragma unroll
    for (int m = 0; m < 4; ++m) {
        float4 v0 = make_float4(0.f,0.f,0.f,0.f), v1 = v0;
        if (col < C) {
            v0 = *(const float4*)(src + m * 8);
            v1 = *(const float4*)(src + m * 8 + 4);
        }
        cs = fmaf(v0.x,v0.x,cs); cs = fmaf(v0.y,v0.y,cs);
        cs = fmaf(v0.z,v0.z,cs); cs = fmaf(v0.w,v0.w,cs);
        cs = fmaf(v1.x,v1.x,cs); cs = fmaf(v1.y,v1.y,cs);
        cs = fmaf(v1.z,v1.z,cs); cs = fmaf(v1.w,v1.w,cs);
        uu[m].x = pk8(v0.x, v0.y, v0.z, v0.w);
        uu[m].y = pk8(v1.x, v1.y, v1.z, v1.w);
    }
    #pragma unroll
    for (int cp = 0; cp < NCOPY; ++cp) {
        unsigned char* dst = wsB + (unsigned)cp * (unsigned)COPYBYTES + tbase;
        #pragma unroll
        for (int m = 0; m < 4; ++m)
            *(uint2*)(dst + ((((unsigned)(q * 4 + m)) * 8u) ^ sw)) = uu[m];
    }
    cs += __shfl_xor(cs, 1); cs += __shfl_xor(cs, 2);
    if (q == 0) {
        float v = (col < C) ? 0.5f * cs : 1e30f;
        #pragma unroll
        for (int cp = 0; cp < NCOPY; ++cp) csqh[cp * 1024 + col] = v;
    }
}

// ---------- main: 128 rows/block, 1024 thr = 16 waves/CU; VGPR capped at 128 ----------
__global__ __launch_bounds__(1024, 4) void center_mfma(
    const float* __restrict__ emb, const int* __restrict__ tgt,
    const float* __restrict__ ctr, const unsigned char* __restrict__ wsB,
    const float* __restrict__ csqh, float* __restrict__ partials)
{
    __shared__ uint4 sB4[8192];   // 128 KB: all 1024 cols fp8, swizzled
    __shared__ uint4 sA4[1024];   // 16 KB: 128 rows fp8, swizzled
    __shared__ float sRT[128];
    __shared__ float sRed[16];
    unsigned char* sAb = (unsigned char*)sA4;
    const unsigned char* sBb = (const unsigned char*)sB4;

    const int t = threadIdx.x;
    const int row0 = blockIdx.x * 128;
    const int cp = blockIdx.x & (NCOPY - 1);
    const unsigned char* wsBx = wsB + (size_t)cp * COPYBYTES;
    const float* csqx = csqh + cp * 1024;

    const int l  = t & 63;
    const int w  = t >> 6;        // 0..15
    const int wr = w >> 2;        // row quarter (32 rows)
    const int wc = w & 3;         // col quarter (32 cols per tile)
    const int li = l & 15;
    const int lh = l >> 4;        // 0..3
    const unsigned sw = (unsigned)li << 3;

    // ---- plain vmem first: A (8 thr/row, 16 dims each) + tgt + csq ----
    const int r = t >> 3, q8 = t & 7;
    const float* srcE = emb + (size_t)(row0 + r) * DD + q8 * 16;
    const int y = tgt[row0 + r];
    const float* srcC = ctr + (size_t)y * DD + q8 * 16;
    float4 ev[4], cv[4];
    #pragma unroll
    for (int m = 0; m < 4; ++m) ev[m] = *(const float4*)(srcE + m * 4);
    #pragma unroll
    for (int m = 0; m < 4; ++m) cv[m] = *(const float4*)(srcC + m * 4);
    float cqa[NTC], cqb[NTC];
    #pragma unroll
    for (int nt = 0; nt < NTC; ++nt) {
        cqa[nt] = csqx[nt*128 + wc*32 + li];
        cqb[nt] = csqx[nt*128 + wc*32 + 16 + li];
    }
    __builtin_amdgcn_sched_barrier(0);   // keep these oldest

    // ---- B one-time load into LDS (in flight under A-pack) ----
    #pragma unroll
    for (int i = 0; i < 8; ++i) {
        unsigned off = (unsigned)(i * 1024 + t) * 16u;
        GLOAD_LDS16(wsBx + off, (unsigned char*)sB4 + off);
    }
    __builtin_amdgcn_sched_barrier(0);

    // ---- A-pack: rt_half + fp8 + swizzled LDS write ----
    {
        const unsigned swA = ((unsigned)r & 15u) << 3;
        float se = 0.f, sd = 0.f;
        #pragma unroll
        for (int m = 0; m < 4; ++m) {
            float4 e0 = ev[m], c0 = cv[m];
            se = fmaf(e0.x,e0.x,se); se = fmaf(e0.y,e0.y,se);
            se = fmaf(e0.z,e0.z,se); se = fmaf(e0.w,e0.w,se);
            float d;
            d = e0.x-c0.x; sd = fmaf(d,d,sd);  d = e0.y-c0.y; sd = fmaf(d,d,sd);
            d = e0.z-c0.z; sd = fmaf(d,d,sd);  d = e0.w-c0.w; sd = fmaf(d,d,sd);
        }
        #pragma unroll
        for (int m = 0; m < 2; ++m) {
            float4 e0 = ev[2*m], e1 = ev[2*m+1];
            uint2 u;
            u.x = pk8(e0.x, e0.y, e0.z, e0.w);
            u.y = pk8(e1.x, e1.y, e1.z, e1.w);
            unsigned j = (unsigned)(q8 * 2 + m);          // slot 0..15
            *(uint2*)(sAb + (unsigned)r * 128u + ((8u * j) ^ swA)) = u;
        }
        se += __shfl_xor(se, 1); se += __shfl_xor(se, 2); se += __shfl_xor(se, 4);
        sd += __shfl_xor(sd, 1); sd += __shfl_xor(sd, 2); sd += __shfl_xor(sd, 4);
        if (q8 == 0) sRT[r] = 0.5f * (1.0f + sd - se);
    }
    __syncthreads();   // A writes + B GLOADs all visible

    // hoist A fragments: row = wr*32 + 16*mf + li; k = 8*lh + 32*ks + e
    i64 aF[2][4];
    #pragma unroll
    for (int mf = 0; mf < 2; ++mf)
        #pragma unroll
        for (int ks = 0; ks < 4; ++ks)
            aF[mf][ks] = *(const i64*)(sAb + (unsigned)(wr*32 + 16*mf + li) * 128u +
                                       (((unsigned)(8*lh + 32*ks)) ^ sw));
    float rtv[8];
    #pragma unroll
    for (int mf = 0; mf < 2; ++mf)
        #pragma unroll
        for (int rr = 0; rr < 4; ++rr)
            rtv[mf*4+rr] = sRT[wr*32 + 16*mf + 4*lh + rr];

    float tsum = 0.f;

    // ---- K-loop: pure LDS + MFMA, no barriers, no vmem ----
    #pragma unroll
    for (int nt = 0; nt < NTC; ++nt) {
        i64 bF0[4], bF1[4];
        #pragma unroll
        for (int ks = 0; ks < 4; ++ks) {
            unsigned kof = ((unsigned)(8*lh + 32*ks)) ^ sw;
            bF0[ks] = *(const i64*)(sBb + (unsigned)nt*16384u +
                                    (unsigned)(wc*32 + li) * 128u + kof);
            bF1[ks] = *(const i64*)(sBb + (unsigned)nt*16384u +
                                    (unsigned)(wc*32 + 16 + li) * 128u + kof);
        }

        f32x4 acc[2][2];
        #pragma unroll
        for (int mf = 0; mf < 2; ++mf)
            #pragma unroll
            for (int rr = 0; rr < 4; ++rr) {
                acc[mf][0][rr] = rtv[mf*4+rr] - cqa[nt];
                acc[mf][1][rr] = rtv[mf*4+rr] - cqb[nt];
            }

        #pragma unroll
        for (int ks = 0; ks < 4; ++ks)
            #pragma unroll
            for (int mf = 0; mf < 2; ++mf) {
                acc[mf][0] = __builtin_amdgcn_mfma_f32_16x16x32_fp8_fp8(aF[mf][ks], bF0[ks], acc[mf][0], 0, 0, 0);
                acc[mf][1] = __builtin_amdgcn_mfma_f32_16x16x32_fp8_fp8(aF[mf][ks], bF1[ks], acc[mf][1], 0, 0, 0);
            }

        float s0 = 0.f, s1 = 0.f;
        #pragma unroll
        for (int mf = 0; mf < 2; ++mf)
            #pragma unroll
            for (int rr = 0; rr < 4; ++rr) {
                s0 = fmaf(2.0f, fmaxf(acc[mf][0][rr], 0.f), s0);
                s1 = fmaf(2.0f, fmaxf(acc[mf][1][rr], 0.f), s1);
            }
        tsum += s0 + s1;
    }

    // ---- block reduction -> deterministic per-block partial ----
    float s = tsum;
    #pragma unroll
    for (int off = 32; off; off >>= 1) s += __shfl_down(s, off);
    if (l == 0) sRed[w] = s;
    __syncthreads();
    if (t == 0) {
        float bs = 0.f;
        #pragma unroll
        for (int i = 0; i < 16; ++i) bs += sRed[i];
        partials[blockIdx.x] = bs;
    }
}

// ---------- final reduction ----------
__global__ void reduce_k(const float* __restrict__ partials, int n,
                         float* __restrict__ out, double diagSub, double invDenom) {
    __shared__ double sRed[4];
    int t = threadIdx.x;
    double s = 0.0;
    for (int i = t; i < n; i += 256) s += (double)partials[i];
    #pragma unroll
    for (int off = 32; off; off >>= 1) s += __shfl_down(s, off);
    if ((t & 63) == 0) sRed[t >> 6] = s;
    __syncthreads();
    if (t == 0) out[0] = (float)(((sRed[0]+sRed[1]+sRed[2]+sRed[3]) - diagSub) * invDenom);
}

extern "C" void kernel_launch(void* const* d_in, const int* in_sizes, int n_in,
                              void* d_out, int out_size, void* d_ws, size_t ws_size,
                              hipStream_t stream) {
    const float* emb = (const float*)d_in[0];
    const int*   tgt = (const int*)d_in[1];
    const float* ctr = (const float*)d_in[2];

    const int B = in_sizes[1];                 // 32768
    const int C = in_sizes[2] / DD;            // 1000
    const int Cpad = NTC * 128;                // 1024
    const int nblk = B / 128;                  // 256 = 1 block/CU

    unsigned char* wsB = (unsigned char*)d_ws;                        // 8 x 128 KB replicas
    float* csqh = (float*)(wsB + (size_t)NCOPY * COPYBYTES);          // 8 x 1024
    float* partials = csqh + NCOPY * 1024;                            // [nblk]

    prep_centers<<<(Cpad * 4) / 256, 256, 0, stream>>>(ctr, wsB, csqh, C, Cpad);
    center_mfma<<<nblk, 1024, 0, stream>>>(emb, tgt, ctr, wsB, csqh, partials);
    reduce_k<<<1, 256, 0, stream>>>(partials, nblk, (float*)d_out,
                                    (double)B,
                                    1.0 / ((double)B * (double)(C - 1)));
}

// Round 17
// 23.063 us; speedup vs baseline: 5.1831x; 1.9893x over previous
//
#include <hip/hip_runtime.h>

#define DD 128
#define NTC 8              // 8 col-tiles of 128 -> Cpad = 1024
#define NCOPY 8            // B replicas (one per XCD under round-robin)
#define COPYBYTES (NTC * 16384)   // 128 KB per replica
#define BM 32              // rows per block -> grid 1024, 4 blocks/CU

typedef __attribute__((ext_vector_type(4))) float f32x4;
typedef long long i64;

typedef __attribute__((address_space(1))) const void gvoid_t;
typedef __attribute__((address_space(3))) void svoid_t;
#define GLOAD_LDS16(g, s) __builtin_amdgcn_global_load_lds((gvoid_t*)(g), (svoid_t*)(s), 16, 0, 0)

__device__ __forceinline__ unsigned pk8(float a, float b, float c, float d) {
    int v = __builtin_amdgcn_cvt_pk_fp8_f32(a, b, 0, false);
    v = __builtin_amdgcn_cvt_pk_fp8_f32(c, d, v, true);
    return (unsigned)v;
}

// ---------- prep: centers -> fp8 e4m3, swizzled, 8 replicas + csq_half x8 ----------
__global__ void prep_centers(const float* __restrict__ ctr,
                             unsigned char* __restrict__ wsB,
                             float* __restrict__ csqh, int C, int Cpad) {
    int gid = blockIdx.x * 256 + threadIdx.x;
    int col = gid >> 2, q = gid & 3;
    if (col >= Cpad) return;
    const float* src = ctr + (size_t)col * DD + q * 32;
    const int r = col & 127;
    const unsigned tbase = (unsigned)(col >> 7) * 16384u + (unsigned)r * 128u;
    const unsigned sw = ((unsigned)r & 15u) << 3;
    float cs = 0.f;
    uint2 uu[4];
    #pragma unroll
    for (int m = 0; m < 4; ++m) {
        float4 v0 = make_float4(0.f,0.f,0.f,0.f), v1 = v0;
        if (col < C) {
            v0 = *(const float4*)(src + m * 8);
            v1 = *(const float4*)(src + m * 8 + 4);
        }
        cs = fmaf(v0.x,v0.x,cs); cs = fmaf(v0.y,v0.y,cs);
        cs = fmaf(v0.z,v0.z,cs); cs = fmaf(v0.w,v0.w,cs);
        cs = fmaf(v1.x,v1.x,cs); cs = fmaf(v1.y,v1.y,cs);
        cs = fmaf(v1.z,v1.z,cs); cs = fmaf(v1.w,v1.w,cs);
        uu[m].x = pk8(v0.x, v0.y, v0.z, v0.w);
        uu[m].y = pk8(v1.x, v1.y, v1.z, v1.w);
    }
    #pragma unroll
    for (int cp = 0; cp < NCOPY; ++cp) {
        unsigned char* dst = wsB + (unsigned)cp * (unsigned)COPYBYTES + tbase;
        #pragma unroll
        for (int m = 0; m < 4; ++m)
            *(uint2*)(dst + ((((unsigned)(q * 4 + m)) * 8u) ^ sw)) = uu[m];
    }
    cs += __shfl_xor(cs, 1); cs += __shfl_xor(cs, 2);
    if (q == 0) {
        float v = (col < C) ? 0.5f * cs : 1e30f;
        #pragma unroll
        for (int cp = 0; cp < NCOPY; ++cp) csqh[cp * 1024 + col] = v;
    }
}

// ---------- main: 32 rows/block, 256 thr, 4 waves; B dbuf-staged; 4 blocks/CU ----------
__global__ __launch_bounds__(256, 4) void center_mfma(
    const float* __restrict__ emb, const int* __restrict__ tgt,
    const float* __restrict__ ctr, const unsigned char* __restrict__ wsB,
    const float* __restrict__ csqh, float* __restrict__ partials)
{
    __shared__ uint4 sB4[2048];   // 2 x 16 KB double buffer (one col-tile each)
    __shared__ uint4 sA4[256];    // 4 KB: 32 rows fp8, swizzled
    __shared__ float sRT[BM];
    __shared__ float sRed[4];
    unsigned char* sAb = (unsigned char*)sA4;
    unsigned char* sB0 = (unsigned char*)sB4;
    unsigned char* sB1 = sB0 + 16384;

    const int t = threadIdx.x;
    const int row0 = blockIdx.x * BM;
    const int cp = blockIdx.x & (NCOPY - 1);
    const unsigned char* wsBx = wsB + (size_t)cp * COPYBYTES;
    const float* csqx = csqh + cp * 1024;

    const int l  = t & 63;
    const int wc = t >> 6;        // wave = col quarter (32 cols per tile)
    const int li = l & 15;
    const int lh = l >> 4;        // 0..3
    const unsigned sw = (unsigned)li << 3;

    // ---- plain vmem first: A (8 thr/row, 16 dims) + tgt + csq ----
    const int r = t >> 3, q8 = t & 7;
    const float* srcE = emb + (size_t)(row0 + r) * DD + q8 * 16;
    const int y = tgt[row0 + r];
    const float* srcC = ctr + (size_t)y * DD + q8 * 16;
    float4 ev[4], cv[4];
    #pragma unroll
    for (int m = 0; m < 4; ++m) ev[m] = *(const float4*)(srcE + m * 4);
    #pragma unroll
    for (int m = 0; m < 4; ++m) cv[m] = *(const float4*)(srcC + m * 4);
    float cqa[NTC], cqb[NTC];
    #pragma unroll
    for (int nt = 0; nt < NTC; ++nt) {
        cqa[nt] = csqx[nt*128 + wc*32 + li];
        cqb[nt] = csqx[nt*128 + wc*32 + 16 + li];
    }
    __builtin_amdgcn_sched_barrier(0);

    // ---- stage(0): 16 KB, 4 GLOAD16/thread ----
    #pragma unroll
    for (int i = 0; i < 4; ++i) {
        unsigned off = (unsigned)(i * 256 + t) * 16u;
        GLOAD_LDS16(wsBx + off, sB0 + off);
    }
    __builtin_amdgcn_sched_barrier(0);

    // ---- A-pack: rt_half + fp8 + swizzled LDS write ----
    {
        const unsigned swA = ((unsigned)r & 15u) << 3;
        float se = 0.f, sd = 0.f;
        #pragma unroll
        for (int m = 0; m < 4; ++m) {
            float4 e0 = ev[m], c0 = cv[m];
            se = fmaf(e0.x,e0.x,se); se = fmaf(e0.y,e0.y,se);
            se = fmaf(e0.z,e0.z,se); se = fmaf(e0.w,e0.w,se);
            float d;
            d = e0.x-c0.x; sd = fmaf(d,d,sd);  d = e0.y-c0.y; sd = fmaf(d,d,sd);
            d = e0.z-c0.z; sd = fmaf(d,d,sd);  d = e0.w-c0.w; sd = fmaf(d,d,sd);
        }
        #pragma unroll
        for (int m = 0; m < 2; ++m) {
            float4 e0 = ev[2*m], e1 = ev[2*m+1];
            uint2 u;
            u.x = pk8(e0.x, e0.y, e0.z, e0.w);
            u.y = pk8(e1.x, e1.y, e1.z, e1.w);
            unsigned j = (unsigned)(q8 * 2 + m);          // slot 0..15
            *(uint2*)(sAb + (unsigned)r * 128u + ((8u * j) ^ swA)) = u;
        }
        se += __shfl_xor(se, 1); se += __shfl_xor(se, 2); se += __shfl_xor(se, 4);
        sd += __shfl_xor(sd, 1); sd += __shfl_xor(sd, 2); sd += __shfl_xor(sd, 4);
        if (q8 == 0) sRT[r] = 0.5f * (1.0f + sd - se);
    }
    __syncthreads();   // A writes visible (stage(0) also drained here)

    // hoist A fragments: row = 16*mf + li; k = 8*lh + 32*ks + e
    i64 aF[2][4];
    #pragma unroll
    for (int mf = 0; mf < 2; ++mf)
        #pragma unroll
        for (int ks = 0; ks < 4; ++ks)
            aF[mf][ks] = *(const i64*)(sAb + (unsigned)(16*mf + li) * 128u +
                                       (((unsigned)(8*lh + 32*ks)) ^ sw));
    float rtv[8];
    #pragma unroll
    for (int mf = 0; mf < 2; ++mf)
        #pragma unroll
        for (int rr = 0; rr < 4; ++rr)
            rtv[mf*4+rr] = sRT[16*mf + 4*lh + rr];

    float tsum = 0.f;

    #pragma unroll
    for (int nt = 0; nt < NTC; ++nt) {
        unsigned char* bufR = (nt & 1) ? sB1 : sB0;
        unsigned char* bufW = (nt & 1) ? sB0 : sB1;

        __syncthreads();   // stage(nt) visible (vmcnt drained at barrier)

        // B fragments of tile nt
        i64 bF0[4], bF1[4];
        #pragma unroll
        for (int ks = 0; ks < 4; ++ks) {
            unsigned kof = ((unsigned)(8*lh + 32*ks)) ^ sw;
            bF0[ks] = *(const i64*)(bufR + (unsigned)(wc*32 + li) * 128u + kof);
            bF1[ks] = *(const i64*)(bufR + (unsigned)(wc*32 + 16 + li) * 128u + kof);
        }
        __syncthreads();   // all reads done; bufW free

        if (nt + 1 < NTC) {   // stage next tile under this tile's MFMA
            const unsigned char* g = wsBx + (size_t)(nt + 1) * 16384;
            #pragma unroll
            for (int i = 0; i < 4; ++i) {
                unsigned off = (unsigned)(i * 256 + t) * 16u;
                GLOAD_LDS16(g + off, bufW + off);
            }
        }

        f32x4 acc[2][2];
        #pragma unroll
        for (int mf = 0; mf < 2; ++mf)
            #pragma unroll
            for (int rr = 0; rr < 4; ++rr) {
                acc[mf][0][rr] = rtv[mf*4+rr] - cqa[nt];
                acc[mf][1][rr] = rtv[mf*4+rr] - cqb[nt];
            }

        #pragma unroll
        for (int ks = 0; ks < 4; ++ks)
            #pragma unroll
            for (int mf = 0; mf < 2; ++mf) {
                acc[mf][0] = __builtin_amdgcn_mfma_f32_16x16x32_fp8_fp8(aF[mf][ks], bF0[ks], acc[mf][0], 0, 0, 0);
                acc[mf][1] = __builtin_amdgcn_mfma_f32_16x16x32_fp8_fp8(aF[mf][ks], bF1[ks], acc[mf][1], 0, 0, 0);
            }

        float s0 = 0.f, s1 = 0.f;
        #pragma unroll
        for (int mf = 0; mf < 2; ++mf)
            #pragma unroll
            for (int rr = 0; rr < 4; ++rr) {
                s0 = fmaf(2.0f, fmaxf(acc[mf][0][rr], 0.f), s0);
                s1 = fmaf(2.0f, fmaxf(acc[mf][1][rr], 0.f), s1);
            }
        tsum += s0 + s1;
    }

    // ---- block reduction -> deterministic per-block partial ----
    float s = tsum;
    #pragma unroll
    for (int off = 32; off; off >>= 1) s += __shfl_down(s, off);
    if (l == 0) sRed[wc] = s;
    __syncthreads();
    if (t == 0) partials[blockIdx.x] = sRed[0] + sRed[1] + sRed[2] + sRed[3];
}

// ---------- final reduction ----------
__global__ void reduce_k(const float* __restrict__ partials, int n,
                         float* __restrict__ out, double diagSub, double invDenom) {
    __shared__ double sRed[4];
    int t = threadIdx.x;
    double s = 0.0;
    for (int i = t; i < n; i += 256) s += (double)partials[i];
    #pragma unroll
    for (int off = 32; off; off >>= 1) s += __shfl_down(s, off);
    if ((t & 63) == 0) sRed[t >> 6] = s;
    __syncthreads();
    if (t == 0) out[0] = (float)(((sRed[0]+sRed[1]+sRed[2]+sRed[3]) - diagSub) * invDenom);
}

extern "C" void kernel_launch(void* const* d_in, const int* in_sizes, int n_in,
                              void* d_out, int out_size, void* d_ws, size_t ws_size,
                              hipStream_t stream) {
    const float* emb = (const float*)d_in[0];
    const int*   tgt = (const int*)d_in[1];
    const float* ctr = (const float*)d_in[2];

    const int B = in_sizes[1];                 // 32768
    const int C = in_sizes[2] / DD;            // 1000
    const int Cpad = NTC * 128;                // 1024
    const int nblk = B / BM;                   // 1024 = 4 blocks/CU

    unsigned char* wsB = (unsigned char*)d_ws;                        // 8 x 128 KB replicas
    float* csqh = (float*)(wsB + (size_t)NCOPY * COPYBYTES);          // 8 x 1024
    float* partials = csqh + NCOPY * 1024;                            // [nblk]

    prep_centers<<<(Cpad * 4) / 256, 256, 0, stream>>>(ctr, wsB, csqh, C, Cpad);
    center_mfma<<<nblk, 256, 0, stream>>>(emb, tgt, ctr, wsB, csqh, partials);
    reduce_k<<<1, 256, 0, stream>>>(partials, nblk, (float*)d_out,
                                    (double)B,
                                    1.0 / ((double)B * (double)(C - 1)));
}